// Round 6
// baseline (405.003 us; speedup 1.0000x reference)
//
#include <hip/hip_runtime.h>
#include <hip/hip_bf16.h>

#define N_NODES 50000
#define N_EDGES 1600000
#define IN_C 256
#define HID_C 256
#define OUT_C 10
#define SLOT_CAP 96      // max degree; Poisson(32) max over 50K nodes ~60; 96 = 11 sigma
#define NBUCKET 196      // ceil(50000/256) dst-buckets of 256 nodes
#define EBUF_CAP 9216    // per-bucket edge capacity; mean 8163, sigma 90 -> +11.7 sigma
#define NSLICE 8         // channel slices, one per XCD (32 ch x 2B = 64B line each)

typedef short bf16x8 __attribute__((ext_vector_type(8)));
typedef short bf16x4 __attribute__((ext_vector_type(4)));
typedef float f32x4 __attribute__((ext_vector_type(4)));

static __device__ __forceinline__ float b2f(short v) {
    unsigned u = (unsigned)(unsigned short)v << 16;
    return __builtin_bit_cast(float, u);
}
static __device__ __forceinline__ short f2b(float f) {
    __hip_bfloat16 h = __float2bfloat16(f);
    return __builtin_bit_cast(short, h);
}

// ---------- phase A: partition edges into 196 dst-buckets (packed 4B records) ----------
__global__ __launch_bounds__(256) void k_part(const int* __restrict__ src,
                                              const int* __restrict__ dst,
                                              int* __restrict__ g_cursor,
                                              int* __restrict__ ebuf) {
    __shared__ int hist[NBUCKET];
    __shared__ int base[NBUCKET];
    __shared__ int pos[NBUCKET];
    int tid = threadIdx.x;
    if (tid < NBUCKET) { hist[tid] = 0; pos[tid] = 0; }
    __syncthreads();

    int4 s[4], d[4];
    bool valid[4];
#pragma unroll
    for (int q = 0; q < 4; ++q) {
        int idx = blockIdx.x * 1024 + q * 256 + tid;    // int4 index, 4 edges each
        valid[q] = (idx < N_EDGES / 4);
        if (valid[q]) {
            s[q] = ((const int4*)src)[idx];
            d[q] = ((const int4*)dst)[idx];
        }
    }
#pragma unroll
    for (int q = 0; q < 4; ++q) {
        if (valid[q]) {
            atomicAdd(&hist[d[q].x >> 8], 1);
            atomicAdd(&hist[d[q].y >> 8], 1);
            atomicAdd(&hist[d[q].z >> 8], 1);
            atomicAdd(&hist[d[q].w >> 8], 1);
        }
    }
    __syncthreads();
    if (tid < NBUCKET && hist[tid] > 0)
        base[tid] = atomicAdd(&g_cursor[tid], hist[tid]);
    __syncthreads();
#pragma unroll
    for (int q = 0; q < 4; ++q) {
        if (valid[q]) {
            int ss[4] = { s[q].x, s[q].y, s[q].z, s[q].w };
            int dd[4] = { d[q].x, d[q].y, d[q].z, d[q].w };
#pragma unroll
            for (int e = 0; e < 4; ++e) {
                int b = dd[e] >> 8;
                int p = base[b] + atomicAdd(&pos[b], 1);
                if (p < EBUF_CAP)
                    ebuf[b * EBUF_CAP + p] = ss[e] | ((dd[e] & 255) << 16);
            }
        }
    }
}

// ---------- phase B: one block per bucket, LDS counters, L2-local slot writes ----------
__global__ __launch_bounds__(256) void k_bucket(const int* __restrict__ ebuf,
                                                const int* __restrict__ g_cursor,
                                                int* __restrict__ cnt,
                                                unsigned short* __restrict__ slots) {
    __shared__ int lcnt[256];
    int b = blockIdx.x, tid = threadIdx.x;
    lcnt[tid] = 0;
    __syncthreads();
    int n_e = g_cursor[b];
    if (n_e > EBUF_CAP) n_e = EBUF_CAP;
    const int* eb = ebuf + b * EBUF_CAP;
    int n4 = n_e >> 2;
    for (int t = tid; t < n4; t += 256) {
        int4 v = ((const int4*)eb)[t];
        int vv[4] = { v.x, v.y, v.z, v.w };
#pragma unroll
        for (int e = 0; e < 4; ++e) {
            int dl = (vv[e] >> 16) & 255;
            int sv = vv[e] & 0xFFFF;
            int p = atomicAdd(&lcnt[dl], 1);
            if (p < SLOT_CAP) slots[(size_t)(b * 256 + dl) * SLOT_CAP + p] = (unsigned short)sv;
        }
    }
    for (int t = (n4 << 2) + tid; t < n_e; t += 256) {
        int vv = eb[t];
        int dl = (vv >> 16) & 255;
        int sv = vv & 0xFFFF;
        int p = atomicAdd(&lcnt[dl], 1);
        if (p < SLOT_CAP) slots[(size_t)(b * 256 + dl) * SLOT_CAP + p] = (unsigned short)sv;
    }
    __syncthreads();
    int nid = b * 256 + tid;
    if (nid < N_NODES) cnt[nid] = lcnt[tid];
}

// ---------- prep ----------
__global__ void k_cvt_x(const float4* __restrict__ x, short4* __restrict__ xb) {
    int i = blockIdx.x * 256 + threadIdx.x;   // N_NODES*IN_C/4 threads exactly
    float4 v = x[i];
    short4 o = { f2b(v.x), f2b(v.y), f2b(v.z), f2b(v.w) };
    xb[i] = o;
}

// Wt[n][k], n in [0,512): n<256 -> W1l[k][n], else W1r[k][n-256]
__global__ void k_prep_w(const float* __restrict__ W1l, const float* __restrict__ W1r,
                         __hip_bfloat16* __restrict__ Wt) {
    int idx = blockIdx.x * 256 + threadIdx.x;  // 512*256
    int n = idx >> 8, k = idx & 255;
    float v = (n < HID_C) ? W1l[k * HID_C + n] : W1r[k * HID_C + (n - HID_C)];
    Wt[idx] = __float2bfloat16(v);
}

// Wt2f rows 0..9 = W2l^T, rows 16..25 = W2r^T, fp32, stride 256
__global__ void k_prep_w2f(const float* __restrict__ W2l, const float* __restrict__ W2r,
                           float* __restrict__ Wt2f) {
    int idx = blockIdx.x * 256 + threadIdx.x;  // 20*256
    int r = idx >> 8, k = idx & 255;
    if (r < OUT_C) Wt2f[r * 256 + k] = W2l[k * OUT_C + r];
    else           Wt2f[(16 + r - OUT_C) * 256 + k] = W2r[k * OUT_C + (r - OUT_C)];
}

// ---------- GEMM1: [AbS | Bh] = Xb @ [W1l | W1r] (+b1 on Bh), 64x64 per wave ----------
// left half written CHANNEL-SLICED: AbS[slice][node][32]
__global__ __launch_bounds__(256) void k_gemm1(
        const __hip_bfloat16* __restrict__ Xb, const __hip_bfloat16* __restrict__ Wt,
        const float* __restrict__ b1,
        __hip_bfloat16* __restrict__ AbS, __hip_bfloat16* __restrict__ Bh) {
    int wave = threadIdx.x >> 6, lane = threadIdx.x & 63;
    int r = lane & 15, quad = lane >> 4;
    int m_base = blockIdx.x * 64;
    int n_base = blockIdx.y * 256 + wave * 64;

    const bf16x8* ap[4];
    const bf16x8* bp[4];
#pragma unroll
    for (int i = 0; i < 4; ++i) {
        int row = m_base + 16 * i + r;
        if (row > N_NODES - 1) row = N_NODES - 1;
        ap[i] = (const bf16x8*)(Xb + (size_t)row * IN_C + quad * 8);
        bp[i] = (const bf16x8*)(Wt + (size_t)(n_base + 16 * i + r) * IN_C + quad * 8);
    }
    f32x4 acc[4][4];
#pragma unroll
    for (int i = 0; i < 4; ++i)
#pragma unroll
        for (int j = 0; j < 4; ++j) acc[i][j] = f32x4{0.f, 0.f, 0.f, 0.f};

#pragma unroll
    for (int kk = 0; kk < IN_C / 32; ++kk) {
        bf16x8 a[4], b[4];
#pragma unroll
        for (int i = 0; i < 4; ++i) a[i] = ap[i][kk * 4];
#pragma unroll
        for (int j = 0; j < 4; ++j) b[j] = bp[j][kk * 4];
#pragma unroll
        for (int i = 0; i < 4; ++i)
#pragma unroll
            for (int j = 0; j < 4; ++j)
                acc[i][j] = __builtin_amdgcn_mfma_f32_16x16x32_bf16(a[i], b[j], acc[i][j], 0, 0, 0);
    }

    bool left = (n_base < HID_C);  // block-uniform
#pragma unroll
    for (int j = 0; j < 4; ++j) {
        int col = n_base + 16 * j + r;
        float bias = left ? 0.f : b1[col - HID_C];
        int sl = (col & 255) >> 5, cc = col & 31;
#pragma unroll
        for (int i = 0; i < 4; ++i) {
#pragma unroll
            for (int ii = 0; ii < 4; ++ii) {
                int row = m_base + 16 * i + quad * 4 + ii;
                if (row < N_NODES) {
                    float v = acc[i][j][ii];
                    if (left) AbS[((size_t)sl * N_NODES + row) * 32 + cc] = __float2bfloat16(v);
                    else      Bh[(size_t)row * HID_C + (col - HID_C)] = __float2bfloat16(v + bias);
                }
            }
        }
    }
}

// ---------- sliced mean-aggregation: slice = blockIdx & 7 (matches XCD round-robin) ----------
// 8 lanes per edge (8B = 4 channels each), 8 edges in flight, x2 unroll
__global__ __launch_bounds__(256) void k_aggs(
        const __hip_bfloat16* __restrict__ AbS, const int* __restrict__ cnt,
        const unsigned short* __restrict__ slots, __hip_bfloat16* __restrict__ Mean) {
    int b = blockIdx.x;                 // 25000 blocks
    int s = b & 7, g = b >> 3;          // slice, node-group (0..3124)
    int wave = threadIdx.x >> 6, lane = threadIdx.x & 63;
    int sub = lane >> 3;                // 0..7: edge-parallel
    int cp  = lane & 7;                 // channel-chunk (4 channels)
    const __hip_bfloat16* base = AbS + (size_t)s * N_NODES * 32 + cp * 4;

#pragma unroll
    for (int i = 0; i < 4; ++i) {
        int nid = g * 16 + wave * 4 + i;    // 3125*16 = 50000 exact
        int n = cnt[nid];
        if (n > SLOT_CAP) n = SLOT_CAP;
        const unsigned short* row = slots + (size_t)nid * SLOT_CAP;

        float a0[4] = {0.f, 0.f, 0.f, 0.f}, a1[4] = {0.f, 0.f, 0.f, 0.f};
        int e = sub;
        for (; e + 8 < n; e += 16) {
            int i0 = row[e], i1 = row[e + 8];
            bf16x4 v0 = *(const bf16x4*)(base + (size_t)i0 * 32);
            bf16x4 v1 = *(const bf16x4*)(base + (size_t)i1 * 32);
#pragma unroll
            for (int j = 0; j < 4; ++j) { a0[j] += b2f(v0[j]); a1[j] += b2f(v1[j]); }
        }
        if (e < n) {
            int i0 = row[e];
            bf16x4 v0 = *(const bf16x4*)(base + (size_t)i0 * 32);
#pragma unroll
            for (int j = 0; j < 4; ++j) a0[j] += b2f(v0[j]);
        }
#pragma unroll
        for (int j = 0; j < 4; ++j) a0[j] += a1[j];
        // reduce across the 8 subs (stride-8 lanes)
#pragma unroll
        for (int j = 0; j < 4; ++j) {
            a0[j] += __shfl_down(a0[j], 32, 64);
            a0[j] += __shfl_down(a0[j], 16, 64);
            a0[j] += __shfl_down(a0[j], 8, 64);
        }
        if (sub == 0) {
            float inv = 1.f / fmaxf((float)n, 1.f);
            bf16x4 o;
#pragma unroll
            for (int j = 0; j < 4; ++j) o[j] = f2b(a0[j] * inv);
            *(bf16x4*)(Mean + (size_t)nid * HID_C + s * 32 + cp * 4) = o;
        }
    }
}

// ---------- relu(Mean + Bh) then h@W2l -> Cp, h@W2r+b2 -> Dp (packed stride 12) ----------
__global__ __launch_bounds__(256) void k_l2(
        const __hip_bfloat16* __restrict__ Mean, const __hip_bfloat16* __restrict__ Bh,
        const float* __restrict__ Wt2f, const float* __restrict__ b2,
        float* __restrict__ Cp, float* __restrict__ Dp) {
    int wave = threadIdx.x >> 6, lane = threadIdx.x & 63;
    int nid = blockIdx.x * 4 + wave;          // grid 12500 -> exact
    int half = lane >> 5;
    int c8 = (lane & 31) * 8;
    // lanes l and l+32 read the same addresses (broadcast-friendly)
    bf16x8 m  = *(const bf16x8*)(Mean + (size_t)nid * HID_C + c8);
    bf16x8 bb = *(const bf16x8*)(Bh + (size_t)nid * HID_C + c8);
    float h[8];
#pragma unroll
    for (int j = 0; j < 8; ++j)
        h[j] = fmaxf(b2f(m[j]) + b2f(bb[j]), 0.f);

    const float* wbase = Wt2f + (half ? 16 * 256 : 0);
    float acc[10];
#pragma unroll
    for (int j = 0; j < 10; ++j) {
        f32x4 w0 = *(const f32x4*)(wbase + j * 256 + c8);
        f32x4 w1 = *(const f32x4*)(wbase + j * 256 + c8 + 4);
        float a = h[0] * w0[0] + h[1] * w0[1] + h[2] * w0[2] + h[3] * w0[3]
                + h[4] * w1[0] + h[5] * w1[1] + h[6] * w1[2] + h[7] * w1[3];
#pragma unroll
        for (int off = 16; off > 0; off >>= 1)
            a += __shfl_down(a, off, 32);
        acc[j] = a;
    }
    if ((lane & 31) == 0) {
        if (half == 0) {
            float* o = Cp + (size_t)nid * 12;
#pragma unroll
            for (int j = 0; j < 10; ++j) o[j] = acc[j];
            o[10] = 0.f; o[11] = 0.f;
        } else {
            float* o = Dp + (size_t)nid * 12;
#pragma unroll
            for (int j = 0; j < 10; ++j) o[j] = acc[j] + b2[j];
        }
    }
}

// ---------- layer2 aggregation + log_softmax: two nodes per wave (32 lanes each) ----------
__global__ __launch_bounds__(256) void k_agg2(
        const float* __restrict__ Cp, const float* __restrict__ Dp,
        const int* __restrict__ cnt, const unsigned short* __restrict__ slots,
        float* __restrict__ out) {
    int wave = threadIdx.x >> 6, lane = threadIdx.x & 63;
    int half = lane >> 5, sub = lane & 31;
    int nid = blockIdx.x * 8 + wave * 2 + half;   // grid 6250 -> exact
    const unsigned short* row = slots + (size_t)nid * SLOT_CAP;
    int n = cnt[nid];
    if (n > SLOT_CAP) n = SLOT_CAP;
    float s[10];
#pragma unroll
    for (int j = 0; j < 10; ++j) s[j] = 0.f;
    for (int e = sub; e < n; e += 32) {
        const float* cr = Cp + (size_t)row[e] * 12;
        f32x4 v0 = *(const f32x4*)cr;
        f32x4 v1 = *(const f32x4*)(cr + 4);
        f32x4 v2 = *(const f32x4*)(cr + 8);   // cols 8..11 (10,11 zeroed)
#pragma unroll
        for (int j = 0; j < 4; ++j) { s[j] += v0[j]; s[4 + j] += v1[j]; }
        s[8] += v2[0]; s[9] += v2[1];
    }
#pragma unroll
    for (int j = 0; j < 10; ++j)
#pragma unroll
        for (int off = 16; off > 0; off >>= 1)
            s[j] += __shfl_down(s[j], off, 32);
    if (sub == 0) {
        float inv = 1.f / fmaxf((float)n, 1.f);
        float z[10], mx = -1e30f;
#pragma unroll
        for (int j = 0; j < 10; ++j) {
            z[j] = s[j] * inv + Dp[(size_t)nid * 12 + j];
            mx = fmaxf(mx, z[j]);
        }
        float se = 0.f;
#pragma unroll
        for (int j = 0; j < 10; ++j) se += expf(z[j] - mx);
        float lse = logf(se) + mx;
#pragma unroll
        for (int j = 0; j < 10; ++j) out[(size_t)nid * OUT_C + j] = z[j] - lse;
    }
}

extern "C" void kernel_launch(void* const* d_in, const int* in_sizes, int n_in,
                              void* d_out, int out_size, void* d_ws, size_t ws_size,
                              hipStream_t stream) {
    const float* x   = (const float*)d_in[0];
    const int*   ei  = (const int*)d_in[1];
    const float* W1l = (const float*)d_in[2];
    const float* W1r = (const float*)d_in[3];
    const float* b1  = (const float*)d_in[4];
    const float* W2l = (const float*)d_in[5];
    const float* W2r = (const float*)d_in[6];
    const float* b2  = (const float*)d_in[7];
    float* out = (float*)d_out;
    const int* src = ei;
    const int* dst = ei + N_EDGES;

    char* w = (char*)d_ws;
    size_t off = 0;
    auto alloc = [&](size_t bytes) -> void* {
        void* p = w + off;
        off = (off + bytes + 255) & ~(size_t)255;
        return p;
    };
    __hip_bfloat16* Xb   = (__hip_bfloat16*)alloc((size_t)N_NODES * IN_C * 2);
    __hip_bfloat16* Wt   = (__hip_bfloat16*)alloc((size_t)2 * HID_C * IN_C * 2);
    float*          Wt2f = (float*)alloc((size_t)32 * 256 * 4);
    __hip_bfloat16* AbS  = (__hip_bfloat16*)alloc((size_t)N_NODES * HID_C * 2);
    __hip_bfloat16* Bh   = (__hip_bfloat16*)alloc((size_t)N_NODES * HID_C * 2);
    float* Cp = (float*)alloc((size_t)N_NODES * 12 * 4);
    float* Dp = (float*)alloc((size_t)N_NODES * 12 * 4);
    int* cnt      = (int*)alloc((size_t)N_NODES * 4);
    unsigned short* slots = (unsigned short*)alloc((size_t)N_NODES * SLOT_CAP * 2);
    int* g_cursor = (int*)alloc((size_t)NBUCKET * 4);
    int* ebuf     = (int*)alloc((size_t)NBUCKET * EBUF_CAP * 4);
    // Mean aliases Xb: Xb is dead after k_gemm1, Mean written by k_aggs afterwards
    __hip_bfloat16* Mean = Xb;

    hipMemsetAsync(g_cursor, 0, (size_t)NBUCKET * 4, stream);

    k_part<<<(N_EDGES / 4 + 1023) / 1024, 256, 0, stream>>>(src, dst, g_cursor, ebuf);
    k_bucket<<<NBUCKET, 256, 0, stream>>>(ebuf, g_cursor, cnt, slots);

    k_cvt_x<<<(N_NODES * IN_C / 4) / 256, 256, 0, stream>>>((const float4*)x, (short4*)Xb);
    k_prep_w<<<512, 256, 0, stream>>>(W1l, W1r, Wt);
    k_prep_w2f<<<20, 256, 0, stream>>>(W2l, W2r, Wt2f);

    k_gemm1<<<dim3((N_NODES + 63) / 64, 2), 256, 0, stream>>>(Xb, Wt, b1, AbS, Bh);
    k_aggs<<<25000, 256, 0, stream>>>(AbS, cnt, slots, Mean);
    k_l2<<<N_NODES / 4, 256, 0, stream>>>(Mean, Bh, Wt2f, b2, Cp, Dp);
    k_agg2<<<N_NODES / 8, 256, 0, stream>>>(Cp, Dp, cnt, slots, out);
}

// Round 7
// 396.557 us; speedup vs baseline: 1.0213x; 1.0213x over previous
//
#include <hip/hip_runtime.h>
#include <hip/hip_bf16.h>

#define N_NODES 50000
#define N_EDGES 1600000
#define IN_C 256
#define HID_C 256
#define OUT_C 10
#define SLOT_CAP 96      // max degree; Poisson(32) max over 50K nodes ~60; 96 = 11 sigma
#define NBUCKET 196      // ceil(50000/256) dst-buckets of 256 nodes
#define EBUF_CAP 9216    // per-bucket edge capacity; mean 8163, sigma 90 -> +11.7 sigma

typedef short bf16x8 __attribute__((ext_vector_type(8)));
typedef float f32x4 __attribute__((ext_vector_type(4)));
typedef unsigned short u16x4 __attribute__((ext_vector_type(4)));

static __device__ __forceinline__ float b2f(short v) {
    unsigned u = (unsigned)(unsigned short)v << 16;
    return __builtin_bit_cast(float, u);
}
static __device__ __forceinline__ short f2b(float f) {
    __hip_bfloat16 h = __float2bfloat16(f);
    return __builtin_bit_cast(short, h);
}

// ---------- phase A: partition edges into 196 dst-buckets (packed 4B records) ----------
__global__ __launch_bounds__(256) void k_part(const int* __restrict__ src,
                                              const int* __restrict__ dst,
                                              int* __restrict__ g_cursor,
                                              int* __restrict__ ebuf) {
    __shared__ int hist[NBUCKET];
    __shared__ int base[NBUCKET];
    __shared__ int pos[NBUCKET];
    int tid = threadIdx.x;
    if (tid < NBUCKET) { hist[tid] = 0; pos[tid] = 0; }
    __syncthreads();

    int4 s[4], d[4];
    bool valid[4];
#pragma unroll
    for (int q = 0; q < 4; ++q) {
        int idx = blockIdx.x * 1024 + q * 256 + tid;    // int4 index, 4 edges each
        valid[q] = (idx < N_EDGES / 4);
        if (valid[q]) {
            s[q] = ((const int4*)src)[idx];
            d[q] = ((const int4*)dst)[idx];
        }
    }
#pragma unroll
    for (int q = 0; q < 4; ++q) {
        if (valid[q]) {
            atomicAdd(&hist[d[q].x >> 8], 1);
            atomicAdd(&hist[d[q].y >> 8], 1);
            atomicAdd(&hist[d[q].z >> 8], 1);
            atomicAdd(&hist[d[q].w >> 8], 1);
        }
    }
    __syncthreads();
    if (tid < NBUCKET && hist[tid] > 0)
        base[tid] = atomicAdd(&g_cursor[tid], hist[tid]);
    __syncthreads();
#pragma unroll
    for (int q = 0; q < 4; ++q) {
        if (valid[q]) {
            int ss[4] = { s[q].x, s[q].y, s[q].z, s[q].w };
            int dd[4] = { d[q].x, d[q].y, d[q].z, d[q].w };
#pragma unroll
            for (int e = 0; e < 4; ++e) {
                int b = dd[e] >> 8;
                int p = base[b] + atomicAdd(&pos[b], 1);
                if (p < EBUF_CAP)
                    ebuf[b * EBUF_CAP + p] = ss[e] | ((dd[e] & 255) << 16);
            }
        }
    }
}

// ---------- phase B: one block per bucket, LDS counters, L2-local slot writes ----------
__global__ __launch_bounds__(256) void k_bucket(const int* __restrict__ ebuf,
                                                const int* __restrict__ g_cursor,
                                                int* __restrict__ cnt,
                                                unsigned short* __restrict__ slots) {
    __shared__ int lcnt[256];
    int b = blockIdx.x, tid = threadIdx.x;
    lcnt[tid] = 0;
    __syncthreads();
    int n_e = g_cursor[b];
    if (n_e > EBUF_CAP) n_e = EBUF_CAP;
    const int* eb = ebuf + b * EBUF_CAP;
    int n4 = n_e >> 2;
    for (int t = tid; t < n4; t += 256) {
        int4 v = ((const int4*)eb)[t];
        int vv[4] = { v.x, v.y, v.z, v.w };
#pragma unroll
        for (int e = 0; e < 4; ++e) {
            int dl = (vv[e] >> 16) & 255;
            int sv = vv[e] & 0xFFFF;
            int p = atomicAdd(&lcnt[dl], 1);
            if (p < SLOT_CAP) slots[(size_t)(b * 256 + dl) * SLOT_CAP + p] = (unsigned short)sv;
        }
    }
    for (int t = (n4 << 2) + tid; t < n_e; t += 256) {
        int vv = eb[t];
        int dl = (vv >> 16) & 255;
        int sv = vv & 0xFFFF;
        int p = atomicAdd(&lcnt[dl], 1);
        if (p < SLOT_CAP) slots[(size_t)(b * 256 + dl) * SLOT_CAP + p] = (unsigned short)sv;
    }
    __syncthreads();
    int nid = b * 256 + tid;
    if (nid < N_NODES) cnt[nid] = lcnt[tid];
}

// ---------- degree-sorted node permutation (96-bin counting sort, 1 block) ----------
__global__ __launch_bounds__(1024) void k_sort(const int* __restrict__ cnt,
                                               int* __restrict__ perm) {
    __shared__ int hist[SLOT_CAP + 1];
    __shared__ int cursor[SLOT_CAP + 1];
    int tid = threadIdx.x;
    if (tid <= SLOT_CAP) hist[tid] = 0;
    __syncthreads();
    for (int i = tid; i < N_NODES; i += 1024) {
        int n = cnt[i]; if (n > SLOT_CAP) n = SLOT_CAP;
        atomicAdd(&hist[n], 1);
    }
    __syncthreads();
    if (tid == 0) {
        int acc = 0;
        for (int b = 0; b <= SLOT_CAP; ++b) { cursor[b] = acc; acc += hist[b]; }
    }
    __syncthreads();
    for (int i = tid; i < N_NODES; i += 1024) {
        int n = cnt[i]; if (n > SLOT_CAP) n = SLOT_CAP;
        int p = atomicAdd(&cursor[n], 1);
        perm[p] = i;
    }
}

// ---------- prep ----------
__global__ void k_cvt_x(const float4* __restrict__ x, short4* __restrict__ xb) {
    int i = blockIdx.x * 256 + threadIdx.x;   // N_NODES*IN_C/4 threads exactly
    float4 v = x[i];
    short4 o = { f2b(v.x), f2b(v.y), f2b(v.z), f2b(v.w) };
    xb[i] = o;
}

// Wt[n][k], n in [0,512): n<256 -> W1l[k][n], else W1r[k][n-256]
__global__ void k_prep_w(const float* __restrict__ W1l, const float* __restrict__ W1r,
                         __hip_bfloat16* __restrict__ Wt) {
    int idx = blockIdx.x * 256 + threadIdx.x;  // 512*256
    int n = idx >> 8, k = idx & 255;
    float v = (n < HID_C) ? W1l[k * HID_C + n] : W1r[k * HID_C + (n - HID_C)];
    Wt[idx] = __float2bfloat16(v);
}

// Wt2f rows 0..9 = W2l^T, rows 16..25 = W2r^T, fp32, stride 256
__global__ void k_prep_w2f(const float* __restrict__ W2l, const float* __restrict__ W2r,
                           float* __restrict__ Wt2f) {
    int idx = blockIdx.x * 256 + threadIdx.x;  // 20*256
    int r = idx >> 8, k = idx & 255;
    if (r < OUT_C) Wt2f[r * 256 + k] = W2l[k * OUT_C + r];
    else           Wt2f[(16 + r - OUT_C) * 256 + k] = W2r[k * OUT_C + (r - OUT_C)];
}

// ---------- GEMM1: [AbS | Bh] = Xb @ [W1l | W1r] (+b1 on Bh), 64x64 per wave ----------
// left half written CHANNEL-SLICED: AbS[slice][node][32]
__global__ __launch_bounds__(256) void k_gemm1(
        const __hip_bfloat16* __restrict__ Xb, const __hip_bfloat16* __restrict__ Wt,
        const float* __restrict__ b1,
        __hip_bfloat16* __restrict__ AbS, __hip_bfloat16* __restrict__ Bh) {
    int wave = threadIdx.x >> 6, lane = threadIdx.x & 63;
    int r = lane & 15, quad = lane >> 4;
    int m_base = blockIdx.x * 64;
    int n_base = blockIdx.y * 256 + wave * 64;

    const bf16x8* ap[4];
    const bf16x8* bp[4];
#pragma unroll
    for (int i = 0; i < 4; ++i) {
        int row = m_base + 16 * i + r;
        if (row > N_NODES - 1) row = N_NODES - 1;
        ap[i] = (const bf16x8*)(Xb + (size_t)row * IN_C + quad * 8);
        bp[i] = (const bf16x8*)(Wt + (size_t)(n_base + 16 * i + r) * IN_C + quad * 8);
    }
    f32x4 acc[4][4];
#pragma unroll
    for (int i = 0; i < 4; ++i)
#pragma unroll
        for (int j = 0; j < 4; ++j) acc[i][j] = f32x4{0.f, 0.f, 0.f, 0.f};

#pragma unroll
    for (int kk = 0; kk < IN_C / 32; ++kk) {
        bf16x8 a[4], b[4];
#pragma unroll
        for (int i = 0; i < 4; ++i) a[i] = ap[i][kk * 4];
#pragma unroll
        for (int j = 0; j < 4; ++j) b[j] = bp[j][kk * 4];
#pragma unroll
        for (int i = 0; i < 4; ++i)
#pragma unroll
            for (int j = 0; j < 4; ++j)
                acc[i][j] = __builtin_amdgcn_mfma_f32_16x16x32_bf16(a[i], b[j], acc[i][j], 0, 0, 0);
    }

    bool left = (n_base < HID_C);  // block-uniform
#pragma unroll
    for (int j = 0; j < 4; ++j) {
        int col = n_base + 16 * j + r;
        float bias = left ? 0.f : b1[col - HID_C];
        int sl = (col & 255) >> 5, cc = col & 31;
#pragma unroll
        for (int i = 0; i < 4; ++i) {
#pragma unroll
            for (int ii = 0; ii < 4; ++ii) {
                int row = m_base + 16 * i + quad * 4 + ii;
                if (row < N_NODES) {
                    float v = acc[i][j][ii];
                    if (left) AbS[((size_t)sl * N_NODES + row) * 32 + cc] = __float2bfloat16(v);
                    else      Bh[(size_t)row * HID_C + (col - HID_C)] = __float2bfloat16(v + bias);
                }
            }
        }
    }
}

// ---------- sliced mean-aggregation: slice = blockIdx & 7 (XCD round-robin) ----------
// 4 lanes own one node's 32-ch slice (8 ch each, 16B loads); sequential edge loop,
// NO cross-lane reduction; degree-sorted perm balances n within a wave.
__global__ __launch_bounds__(256) void k_aggs(
        const __hip_bfloat16* __restrict__ AbS, const int* __restrict__ cnt,
        const unsigned short* __restrict__ slots, const int* __restrict__ perm,
        __hip_bfloat16* __restrict__ Mean) {
    int b = blockIdx.x;                 // 8 * 782 = 6256
    int s = b & 7, g = b >> 3;          // slice, node-group
    int wave = threadIdx.x >> 6, lane = threadIdx.x & 63;
    int grp = lane >> 2;                // 0..15: node within wave
    int cp  = lane & 3;                 // channel chunk (8 ch)
    int idx = g * 64 + wave * 16 + grp;
    if (idx >= N_NODES) return;
    int nid = perm[idx];
    int n = cnt[nid];
    if (n > SLOT_CAP) n = SLOT_CAP;
    const unsigned short* row = slots + (size_t)nid * SLOT_CAP;
    const __hip_bfloat16* base = AbS + (size_t)s * N_NODES * 32 + cp * 8;

    float a0[8], a1[8];
#pragma unroll
    for (int j = 0; j < 8; ++j) { a0[j] = 0.f; a1[j] = 0.f; }

    int e = 0;
    for (; e + 4 <= n; e += 4) {
        u16x4 r4 = *(const u16x4*)(row + e);   // 8B index prefetch (4 edges)
        bf16x8 v0 = *(const bf16x8*)(base + (size_t)r4[0] * 32);
        bf16x8 v1 = *(const bf16x8*)(base + (size_t)r4[1] * 32);
        bf16x8 v2 = *(const bf16x8*)(base + (size_t)r4[2] * 32);
        bf16x8 v3 = *(const bf16x8*)(base + (size_t)r4[3] * 32);
#pragma unroll
        for (int j = 0; j < 8; ++j) {
            a0[j] += b2f(v0[j]); a1[j] += b2f(v1[j]);
            a0[j] += b2f(v2[j]); a1[j] += b2f(v3[j]);
        }
    }
    for (; e < n; ++e) {
        bf16x8 v0 = *(const bf16x8*)(base + (size_t)row[e] * 32);
#pragma unroll
        for (int j = 0; j < 8; ++j) a0[j] += b2f(v0[j]);
    }

    float inv = 1.f / fmaxf((float)n, 1.f);
    bf16x8 o;
#pragma unroll
    for (int j = 0; j < 8; ++j) o[j] = f2b((a0[j] + a1[j]) * inv);
    *(bf16x8*)(Mean + (size_t)nid * HID_C + s * 32 + cp * 8) = o;
}

// ---------- relu(Mean + Bh) then h@W2l -> Cp, h@W2r+b2 -> Dp (packed stride 12) ----------
__global__ __launch_bounds__(256) void k_l2(
        const __hip_bfloat16* __restrict__ Mean, const __hip_bfloat16* __restrict__ Bh,
        const float* __restrict__ Wt2f, const float* __restrict__ b2,
        float* __restrict__ Cp, float* __restrict__ Dp) {
    int wave = threadIdx.x >> 6, lane = threadIdx.x & 63;
    int nid = blockIdx.x * 4 + wave;          // grid 12500 -> exact
    int half = lane >> 5;
    int c8 = (lane & 31) * 8;
    bf16x8 m  = *(const bf16x8*)(Mean + (size_t)nid * HID_C + c8);
    bf16x8 bb = *(const bf16x8*)(Bh + (size_t)nid * HID_C + c8);
    float h[8];
#pragma unroll
    for (int j = 0; j < 8; ++j)
        h[j] = fmaxf(b2f(m[j]) + b2f(bb[j]), 0.f);

    const float* wbase = Wt2f + (half ? 16 * 256 : 0);
    float acc[10];
#pragma unroll
    for (int j = 0; j < 10; ++j) {
        f32x4 w0 = *(const f32x4*)(wbase + j * 256 + c8);
        f32x4 w1 = *(const f32x4*)(wbase + j * 256 + c8 + 4);
        float a = h[0] * w0[0] + h[1] * w0[1] + h[2] * w0[2] + h[3] * w0[3]
                + h[4] * w1[0] + h[5] * w1[1] + h[6] * w1[2] + h[7] * w1[3];
#pragma unroll
        for (int off = 16; off > 0; off >>= 1)
            a += __shfl_down(a, off, 32);
        acc[j] = a;
    }
    if ((lane & 31) == 0) {
        if (half == 0) {
            float* o = Cp + (size_t)nid * 12;
#pragma unroll
            for (int j = 0; j < 10; ++j) o[j] = acc[j];
            o[10] = 0.f; o[11] = 0.f;
        } else {
            float* o = Dp + (size_t)nid * 12;
#pragma unroll
            for (int j = 0; j < 10; ++j) o[j] = acc[j] + b2[j];
        }
    }
}

// ---------- layer2 aggregation + log_softmax: two nodes per wave (32 lanes each) ----------
__global__ __launch_bounds__(256) void k_agg2(
        const float* __restrict__ Cp, const float* __restrict__ Dp,
        const int* __restrict__ cnt, const unsigned short* __restrict__ slots,
        const int* __restrict__ perm, float* __restrict__ out) {
    int wave = threadIdx.x >> 6, lane = threadIdx.x & 63;
    int half = lane >> 5, sub = lane & 31;
    int idx = blockIdx.x * 8 + wave * 2 + half;   // grid 6250 -> exact
    int nid = perm[idx];
    const unsigned short* row = slots + (size_t)nid * SLOT_CAP;
    int n = cnt[nid];
    if (n > SLOT_CAP) n = SLOT_CAP;
    float s[10];
#pragma unroll
    for (int j = 0; j < 10; ++j) s[j] = 0.f;
    for (int e = sub; e < n; e += 32) {
        const float* cr = Cp + (size_t)row[e] * 12;
        f32x4 v0 = *(const f32x4*)cr;
        f32x4 v1 = *(const f32x4*)(cr + 4);
        f32x4 v2 = *(const f32x4*)(cr + 8);   // cols 8..11 (10,11 zeroed)
#pragma unroll
        for (int j = 0; j < 4; ++j) { s[j] += v0[j]; s[4 + j] += v1[j]; }
        s[8] += v2[0]; s[9] += v2[1];
    }
#pragma unroll
    for (int j = 0; j < 10; ++j)
#pragma unroll
        for (int off = 16; off > 0; off >>= 1)
            s[j] += __shfl_down(s[j], off, 32);
    if (sub == 0) {
        float inv = 1.f / fmaxf((float)n, 1.f);
        float z[10], mx = -1e30f;
#pragma unroll
        for (int j = 0; j < 10; ++j) {
            z[j] = s[j] * inv + Dp[(size_t)nid * 12 + j];
            mx = fmaxf(mx, z[j]);
        }
        float se = 0.f;
#pragma unroll
        for (int j = 0; j < 10; ++j) se += expf(z[j] - mx);
        float lse = logf(se) + mx;
#pragma unroll
        for (int j = 0; j < 10; ++j) out[(size_t)nid * OUT_C + j] = z[j] - lse;
    }
}

extern "C" void kernel_launch(void* const* d_in, const int* in_sizes, int n_in,
                              void* d_out, int out_size, void* d_ws, size_t ws_size,
                              hipStream_t stream) {
    const float* x   = (const float*)d_in[0];
    const int*   ei  = (const int*)d_in[1];
    const float* W1l = (const float*)d_in[2];
    const float* W1r = (const float*)d_in[3];
    const float* b1  = (const float*)d_in[4];
    const float* W2l = (const float*)d_in[5];
    const float* W2r = (const float*)d_in[6];
    const float* b2  = (const float*)d_in[7];
    float* out = (float*)d_out;
    const int* src = ei;
    const int* dst = ei + N_EDGES;

    char* w = (char*)d_ws;
    size_t off = 0;
    auto alloc = [&](size_t bytes) -> void* {
        void* p = w + off;
        off = (off + bytes + 255) & ~(size_t)255;
        return p;
    };
    __hip_bfloat16* Xb   = (__hip_bfloat16*)alloc((size_t)N_NODES * IN_C * 2);
    __hip_bfloat16* Wt   = (__hip_bfloat16*)alloc((size_t)2 * HID_C * IN_C * 2);
    float*          Wt2f = (float*)alloc((size_t)32 * 256 * 4);
    __hip_bfloat16* AbS  = (__hip_bfloat16*)alloc((size_t)N_NODES * HID_C * 2);
    __hip_bfloat16* Bh   = (__hip_bfloat16*)alloc((size_t)N_NODES * HID_C * 2);
    float* Cp = (float*)alloc((size_t)N_NODES * 12 * 4);
    float* Dp = (float*)alloc((size_t)N_NODES * 12 * 4);
    int* cnt      = (int*)alloc((size_t)N_NODES * 4);
    unsigned short* slots = (unsigned short*)alloc((size_t)N_NODES * SLOT_CAP * 2);
    int* perm     = (int*)alloc((size_t)N_NODES * 4);
    int* g_cursor = (int*)alloc((size_t)NBUCKET * 4);
    int* ebuf     = (int*)alloc((size_t)NBUCKET * EBUF_CAP * 4);
    // Mean aliases Xb: Xb is dead after k_gemm1, Mean written by k_aggs afterwards
    __hip_bfloat16* Mean = Xb;

    hipMemsetAsync(g_cursor, 0, (size_t)NBUCKET * 4, stream);

    k_part<<<(N_EDGES / 4 + 1023) / 1024, 256, 0, stream>>>(src, dst, g_cursor, ebuf);
    k_bucket<<<NBUCKET, 256, 0, stream>>>(ebuf, g_cursor, cnt, slots);
    k_sort<<<1, 1024, 0, stream>>>(cnt, perm);

    k_cvt_x<<<(N_NODES * IN_C / 4) / 256, 256, 0, stream>>>((const float4*)x, (short4*)Xb);
    k_prep_w<<<512, 256, 0, stream>>>(W1l, W1r, Wt);
    k_prep_w2f<<<20, 256, 0, stream>>>(W2l, W2r, Wt2f);

    k_gemm1<<<dim3((N_NODES + 63) / 64, 2), 256, 0, stream>>>(Xb, Wt, b1, AbS, Bh);
    k_aggs<<<8 * ((N_NODES + 63) / 64), 256, 0, stream>>>(AbS, cnt, slots, perm, Mean);
    k_l2<<<N_NODES / 4, 256, 0, stream>>>(Mean, Bh, Wt2f, b2, Cp, Dp);
    k_agg2<<<N_NODES / 8, 256, 0, stream>>>(Cp, Dp, cnt, slots, perm, out);
}

// Round 8
// 370.226 us; speedup vs baseline: 1.0939x; 1.0711x over previous
//
#include <hip/hip_runtime.h>
#include <hip/hip_bf16.h>

#define N_NODES 50000
#define N_EDGES 1600000
#define IN_C 256
#define HID_C 256
#define OUT_C 10
#define SLOT_CAP 96      // max degree; Poisson(32) max over 50K nodes ~60; 96 = 11 sigma
#define NBUCKET 196      // ceil(50000/256) dst-buckets of 256 nodes
#define EBUF_CAP 9216    // per-bucket edge capacity; mean 8163, sigma 90 -> +11.7 sigma

typedef short bf16x8 __attribute__((ext_vector_type(8)));
typedef float f32x4 __attribute__((ext_vector_type(4)));
typedef unsigned short u16x4 __attribute__((ext_vector_type(4)));

static __device__ __forceinline__ float b2f(short v) {
    unsigned u = (unsigned)(unsigned short)v << 16;
    return __builtin_bit_cast(float, u);
}
static __device__ __forceinline__ short f2b(float f) {
    __hip_bfloat16 h = __float2bfloat16(f);
    return __builtin_bit_cast(short, h);
}

// ---------- phase A: partition edges into 196 dst-buckets (packed 4B records) ----------
__global__ __launch_bounds__(256) void k_part(const int* __restrict__ src,
                                              const int* __restrict__ dst,
                                              int* __restrict__ g_cursor,
                                              int* __restrict__ ebuf) {
    __shared__ int hist[NBUCKET];
    __shared__ int base[NBUCKET];
    __shared__ int pos[NBUCKET];
    int tid = threadIdx.x;
    if (tid < NBUCKET) { hist[tid] = 0; pos[tid] = 0; }
    __syncthreads();

    int4 s[4], d[4];
    bool valid[4];
#pragma unroll
    for (int q = 0; q < 4; ++q) {
        int idx = blockIdx.x * 1024 + q * 256 + tid;    // int4 index, 4 edges each
        valid[q] = (idx < N_EDGES / 4);
        if (valid[q]) {
            s[q] = ((const int4*)src)[idx];
            d[q] = ((const int4*)dst)[idx];
        }
    }
#pragma unroll
    for (int q = 0; q < 4; ++q) {
        if (valid[q]) {
            atomicAdd(&hist[d[q].x >> 8], 1);
            atomicAdd(&hist[d[q].y >> 8], 1);
            atomicAdd(&hist[d[q].z >> 8], 1);
            atomicAdd(&hist[d[q].w >> 8], 1);
        }
    }
    __syncthreads();
    if (tid < NBUCKET && hist[tid] > 0)
        base[tid] = atomicAdd(&g_cursor[tid], hist[tid]);
    __syncthreads();
#pragma unroll
    for (int q = 0; q < 4; ++q) {
        if (valid[q]) {
            int ss[4] = { s[q].x, s[q].y, s[q].z, s[q].w };
            int dd[4] = { d[q].x, d[q].y, d[q].z, d[q].w };
#pragma unroll
            for (int e = 0; e < 4; ++e) {
                int b = dd[e] >> 8;
                int p = base[b] + atomicAdd(&pos[b], 1);
                if (p < EBUF_CAP)
                    ebuf[b * EBUF_CAP + p] = ss[e] | ((dd[e] & 255) << 16);
            }
        }
    }
}

// ---------- phase B: one block per bucket, LDS counters, L2-local slot writes ----------
__global__ __launch_bounds__(256) void k_bucket(const int* __restrict__ ebuf,
                                                const int* __restrict__ g_cursor,
                                                int* __restrict__ cnt,
                                                unsigned short* __restrict__ slots) {
    __shared__ int lcnt[256];
    int b = blockIdx.x, tid = threadIdx.x;
    lcnt[tid] = 0;
    __syncthreads();
    int n_e = g_cursor[b];
    if (n_e > EBUF_CAP) n_e = EBUF_CAP;
    const int* eb = ebuf + b * EBUF_CAP;
    int n4 = n_e >> 2;
    for (int t = tid; t < n4; t += 256) {
        int4 v = ((const int4*)eb)[t];
        int vv[4] = { v.x, v.y, v.z, v.w };
#pragma unroll
        for (int e = 0; e < 4; ++e) {
            int dl = (vv[e] >> 16) & 255;
            int sv = vv[e] & 0xFFFF;
            int p = atomicAdd(&lcnt[dl], 1);
            if (p < SLOT_CAP) slots[(size_t)(b * 256 + dl) * SLOT_CAP + p] = (unsigned short)sv;
        }
    }
    for (int t = (n4 << 2) + tid; t < n_e; t += 256) {
        int vv = eb[t];
        int dl = (vv >> 16) & 255;
        int sv = vv & 0xFFFF;
        int p = atomicAdd(&lcnt[dl], 1);
        if (p < SLOT_CAP) slots[(size_t)(b * 256 + dl) * SLOT_CAP + p] = (unsigned short)sv;
    }
    __syncthreads();
    int nid = b * 256 + tid;
    if (nid < N_NODES) cnt[nid] = lcnt[tid];
}

// ---------- WINDOWED degree sort: rank-sort 64-node windows (preserves locality) ----------
__global__ __launch_bounds__(64) void k_sortw(const int* __restrict__ cnt,
                                              int* __restrict__ perm) {
    __shared__ int deg[64];
    int w = blockIdx.x, t = threadIdx.x;   // 782 windows
    int nid = w * 64 + t;
    bool valid = (nid < N_NODES);
    int n = valid ? cnt[nid] : 0x7FFFFFFF;
    if (n > SLOT_CAP && valid) n = SLOT_CAP;
    deg[t] = n;
    __syncthreads();
    if (valid) {
        int rank = 0;
#pragma unroll 16
        for (int j = 0; j < 64; ++j) {
            int nj = deg[j];
            rank += (nj < n || (nj == n && j < t)) ? 1 : 0;
        }
        perm[w * 64 + rank] = nid;
    }
}

// ---------- prep ----------
__global__ void k_cvt_x(const float4* __restrict__ x, short4* __restrict__ xb) {
    int i = blockIdx.x * 256 + threadIdx.x;   // N_NODES*IN_C/4 threads exactly
    float4 v = x[i];
    short4 o = { f2b(v.x), f2b(v.y), f2b(v.z), f2b(v.w) };
    xb[i] = o;
}

// Wt[n][k], n in [0,512): n<256 -> W1l[k][n], else W1r[k][n-256]
__global__ void k_prep_w(const float* __restrict__ W1l, const float* __restrict__ W1r,
                         __hip_bfloat16* __restrict__ Wt) {
    int idx = blockIdx.x * 256 + threadIdx.x;  // 512*256
    int n = idx >> 8, k = idx & 255;
    float v = (n < HID_C) ? W1l[k * HID_C + n] : W1r[k * HID_C + (n - HID_C)];
    Wt[idx] = __float2bfloat16(v);
}

// Wt2f rows 0..9 = W2l^T, rows 16..25 = W2r^T, fp32, stride 256
__global__ void k_prep_w2f(const float* __restrict__ W2l, const float* __restrict__ W2r,
                           float* __restrict__ Wt2f) {
    int idx = blockIdx.x * 256 + threadIdx.x;  // 20*256
    int r = idx >> 8, k = idx & 255;
    if (r < OUT_C) Wt2f[r * 256 + k] = W2l[k * OUT_C + r];
    else           Wt2f[(16 + r - OUT_C) * 256 + k] = W2r[k * OUT_C + (r - OUT_C)];
}

// ---------- GEMM1: [AbS | Bh] = Xb @ [W1l | W1r] (+b1 on Bh), 64x64 per wave ----------
// left half written CHANNEL-SLICED: AbS[slice][node][32]
__global__ __launch_bounds__(256) void k_gemm1(
        const __hip_bfloat16* __restrict__ Xb, const __hip_bfloat16* __restrict__ Wt,
        const float* __restrict__ b1,
        __hip_bfloat16* __restrict__ AbS, __hip_bfloat16* __restrict__ Bh) {
    int wave = threadIdx.x >> 6, lane = threadIdx.x & 63;
    int r = lane & 15, quad = lane >> 4;
    int m_base = blockIdx.x * 64;
    int n_base = blockIdx.y * 256 + wave * 64;

    const bf16x8* ap[4];
    const bf16x8* bp[4];
#pragma unroll
    for (int i = 0; i < 4; ++i) {
        int row = m_base + 16 * i + r;
        if (row > N_NODES - 1) row = N_NODES - 1;
        ap[i] = (const bf16x8*)(Xb + (size_t)row * IN_C + quad * 8);
        bp[i] = (const bf16x8*)(Wt + (size_t)(n_base + 16 * i + r) * IN_C + quad * 8);
    }
    f32x4 acc[4][4];
#pragma unroll
    for (int i = 0; i < 4; ++i)
#pragma unroll
        for (int j = 0; j < 4; ++j) acc[i][j] = f32x4{0.f, 0.f, 0.f, 0.f};

#pragma unroll
    for (int kk = 0; kk < IN_C / 32; ++kk) {
        bf16x8 a[4], b[4];
#pragma unroll
        for (int i = 0; i < 4; ++i) a[i] = ap[i][kk * 4];
#pragma unroll
        for (int j = 0; j < 4; ++j) b[j] = bp[j][kk * 4];
#pragma unroll
        for (int i = 0; i < 4; ++i)
#pragma unroll
            for (int j = 0; j < 4; ++j)
                acc[i][j] = __builtin_amdgcn_mfma_f32_16x16x32_bf16(a[i], b[j], acc[i][j], 0, 0, 0);
    }

    bool left = (n_base < HID_C);  // block-uniform
#pragma unroll
    for (int j = 0; j < 4; ++j) {
        int col = n_base + 16 * j + r;
        float bias = left ? 0.f : b1[col - HID_C];
        int sl = (col & 255) >> 5, cc = col & 31;
#pragma unroll
        for (int i = 0; i < 4; ++i) {
#pragma unroll
            for (int ii = 0; ii < 4; ++ii) {
                int row = m_base + 16 * i + quad * 4 + ii;
                if (row < N_NODES) {
                    float v = acc[i][j][ii];
                    if (left) AbS[((size_t)sl * N_NODES + row) * 32 + cc] = __float2bfloat16(v);
                    else      Bh[(size_t)row * HID_C + (col - HID_C)] = __float2bfloat16(v + bias);
                }
            }
        }
    }
}

// ---------- sliced mean-aggregation: slice = blockIdx & 7 (XCD round-robin) ----------
// 4 lanes own one node's 32-ch slice (8 ch each, 16B loads); sequential edge loop,
// no cross-lane reduction; WINDOWED degree-sorted perm keeps nid locality.
__global__ __launch_bounds__(256) void k_aggs(
        const __hip_bfloat16* __restrict__ AbS, const int* __restrict__ cnt,
        const unsigned short* __restrict__ slots, const int* __restrict__ perm,
        __hip_bfloat16* __restrict__ Mean) {
    int b = blockIdx.x;                 // 8 * 782 = 6256
    int s = b & 7, g = b >> 3;          // slice, node-window
    int wave = threadIdx.x >> 6, lane = threadIdx.x & 63;
    int grp = lane >> 2;                // 0..15: node within wave
    int cp  = lane & 3;                 // channel chunk (8 ch)
    int idx = g * 64 + wave * 16 + grp;
    if (idx >= N_NODES) return;
    int nid = perm[idx];
    int n = cnt[nid];
    if (n > SLOT_CAP) n = SLOT_CAP;
    const unsigned short* row = slots + (size_t)nid * SLOT_CAP;
    const __hip_bfloat16* base = AbS + (size_t)s * N_NODES * 32 + cp * 8;

    float a0[8], a1[8];
#pragma unroll
    for (int j = 0; j < 8; ++j) { a0[j] = 0.f; a1[j] = 0.f; }

    int e = 0;
    for (; e + 4 <= n; e += 4) {
        u16x4 r4 = *(const u16x4*)(row + e);   // 8B index prefetch (4 edges)
        bf16x8 v0 = *(const bf16x8*)(base + (size_t)r4[0] * 32);
        bf16x8 v1 = *(const bf16x8*)(base + (size_t)r4[1] * 32);
        bf16x8 v2 = *(const bf16x8*)(base + (size_t)r4[2] * 32);
        bf16x8 v3 = *(const bf16x8*)(base + (size_t)r4[3] * 32);
#pragma unroll
        for (int j = 0; j < 8; ++j) {
            a0[j] += b2f(v0[j]); a1[j] += b2f(v1[j]);
            a0[j] += b2f(v2[j]); a1[j] += b2f(v3[j]);
        }
    }
    for (; e < n; ++e) {
        bf16x8 v0 = *(const bf16x8*)(base + (size_t)row[e] * 32);
#pragma unroll
        for (int j = 0; j < 8; ++j) a0[j] += b2f(v0[j]);
    }

    float inv = 1.f / fmaxf((float)n, 1.f);
    bf16x8 o;
#pragma unroll
    for (int j = 0; j < 8; ++j) o[j] = f2b((a0[j] + a1[j]) * inv);
    *(bf16x8*)(Mean + (size_t)nid * HID_C + s * 32 + cp * 8) = o;
}

// ---------- relu(Mean + Bh) then h@W2l -> Cp, h@W2r+b2 -> Dp (packed stride 12) ----------
__global__ __launch_bounds__(256) void k_l2(
        const __hip_bfloat16* __restrict__ Mean, const __hip_bfloat16* __restrict__ Bh,
        const float* __restrict__ Wt2f, const float* __restrict__ b2,
        float* __restrict__ Cp, float* __restrict__ Dp) {
    int wave = threadIdx.x >> 6, lane = threadIdx.x & 63;
    int nid = blockIdx.x * 4 + wave;          // grid 12500 -> exact
    int half = lane >> 5;
    int c8 = (lane & 31) * 8;
    bf16x8 m  = *(const bf16x8*)(Mean + (size_t)nid * HID_C + c8);
    bf16x8 bb = *(const bf16x8*)(Bh + (size_t)nid * HID_C + c8);
    float h[8];
#pragma unroll
    for (int j = 0; j < 8; ++j)
        h[j] = fmaxf(b2f(m[j]) + b2f(bb[j]), 0.f);

    const float* wbase = Wt2f + (half ? 16 * 256 : 0);
    float acc[10];
#pragma unroll
    for (int j = 0; j < 10; ++j) {
        f32x4 w0 = *(const f32x4*)(wbase + j * 256 + c8);
        f32x4 w1 = *(const f32x4*)(wbase + j * 256 + c8 + 4);
        float a = h[0] * w0[0] + h[1] * w0[1] + h[2] * w0[2] + h[3] * w0[3]
                + h[4] * w1[0] + h[5] * w1[1] + h[6] * w1[2] + h[7] * w1[3];
#pragma unroll
        for (int off = 16; off > 0; off >>= 1)
            a += __shfl_down(a, off, 32);
        acc[j] = a;
    }
    if ((lane & 31) == 0) {
        if (half == 0) {
            float* o = Cp + (size_t)nid * 12;
#pragma unroll
            for (int j = 0; j < 10; ++j) o[j] = acc[j];
            o[10] = 0.f; o[11] = 0.f;
        } else {
            float* o = Dp + (size_t)nid * 12;
#pragma unroll
            for (int j = 0; j < 10; ++j) o[j] = acc[j] + b2[j];
        }
    }
}

// ---------- layer2 aggregation + log_softmax: two nodes per wave (32 lanes each) ----------
__global__ __launch_bounds__(256) void k_agg2(
        const float* __restrict__ Cp, const float* __restrict__ Dp,
        const int* __restrict__ cnt, const unsigned short* __restrict__ slots,
        const int* __restrict__ perm, float* __restrict__ out) {
    int wave = threadIdx.x >> 6, lane = threadIdx.x & 63;
    int half = lane >> 5, sub = lane & 31;
    int idx = blockIdx.x * 8 + wave * 2 + half;   // grid 6250 -> exact
    int nid = perm[idx];
    const unsigned short* row = slots + (size_t)nid * SLOT_CAP;
    int n = cnt[nid];
    if (n > SLOT_CAP) n = SLOT_CAP;
    float s[10];
#pragma unroll
    for (int j = 0; j < 10; ++j) s[j] = 0.f;
    for (int e = sub; e < n; e += 32) {
        const float* cr = Cp + (size_t)row[e] * 12;
        f32x4 v0 = *(const f32x4*)cr;
        f32x4 v1 = *(const f32x4*)(cr + 4);
        f32x4 v2 = *(const f32x4*)(cr + 8);   // cols 8..11 (10,11 zeroed)
#pragma unroll
        for (int j = 0; j < 4; ++j) { s[j] += v0[j]; s[4 + j] += v1[j]; }
        s[8] += v2[0]; s[9] += v2[1];
    }
#pragma unroll
    for (int j = 0; j < 10; ++j)
#pragma unroll
        for (int off = 16; off > 0; off >>= 1)
            s[j] += __shfl_down(s[j], off, 32);
    if (sub == 0) {
        float inv = 1.f / fmaxf((float)n, 1.f);
        float z[10], mx = -1e30f;
#pragma unroll
        for (int j = 0; j < 10; ++j) {
            z[j] = s[j] * inv + Dp[(size_t)nid * 12 + j];
            mx = fmaxf(mx, z[j]);
        }
        float se = 0.f;
#pragma unroll
        for (int j = 0; j < 10; ++j) se += expf(z[j] - mx);
        float lse = logf(se) + mx;
#pragma unroll
        for (int j = 0; j < 10; ++j) out[(size_t)nid * OUT_C + j] = z[j] - lse;
    }
}

extern "C" void kernel_launch(void* const* d_in, const int* in_sizes, int n_in,
                              void* d_out, int out_size, void* d_ws, size_t ws_size,
                              hipStream_t stream) {
    const float* x   = (const float*)d_in[0];
    const int*   ei  = (const int*)d_in[1];
    const float* W1l = (const float*)d_in[2];
    const float* W1r = (const float*)d_in[3];
    const float* b1  = (const float*)d_in[4];
    const float* W2l = (const float*)d_in[5];
    const float* W2r = (const float*)d_in[6];
    const float* b2  = (const float*)d_in[7];
    float* out = (float*)d_out;
    const int* src = ei;
    const int* dst = ei + N_EDGES;

    char* w = (char*)d_ws;
    size_t off = 0;
    auto alloc = [&](size_t bytes) -> void* {
        void* p = w + off;
        off = (off + bytes + 255) & ~(size_t)255;
        return p;
    };
    __hip_bfloat16* Xb   = (__hip_bfloat16*)alloc((size_t)N_NODES * IN_C * 2);
    __hip_bfloat16* Wt   = (__hip_bfloat16*)alloc((size_t)2 * HID_C * IN_C * 2);
    float*          Wt2f = (float*)alloc((size_t)32 * 256 * 4);
    __hip_bfloat16* AbS  = (__hip_bfloat16*)alloc((size_t)N_NODES * HID_C * 2);
    __hip_bfloat16* Bh   = (__hip_bfloat16*)alloc((size_t)N_NODES * HID_C * 2);
    float* Cp = (float*)alloc((size_t)N_NODES * 12 * 4);
    float* Dp = (float*)alloc((size_t)N_NODES * 12 * 4);
    int* cnt      = (int*)alloc((size_t)N_NODES * 4);
    unsigned short* slots = (unsigned short*)alloc((size_t)N_NODES * SLOT_CAP * 2);
    int* perm     = (int*)alloc((size_t)N_NODES * 4);
    int* g_cursor = (int*)alloc((size_t)NBUCKET * 4);
    int* ebuf     = (int*)alloc((size_t)NBUCKET * EBUF_CAP * 4);
    // Mean aliases Xb: Xb is dead after k_gemm1, Mean written by k_aggs afterwards
    __hip_bfloat16* Mean = Xb;

    hipMemsetAsync(g_cursor, 0, (size_t)NBUCKET * 4, stream);

    k_part<<<(N_EDGES / 4 + 1023) / 1024, 256, 0, stream>>>(src, dst, g_cursor, ebuf);
    k_bucket<<<NBUCKET, 256, 0, stream>>>(ebuf, g_cursor, cnt, slots);
    k_sortw<<<(N_NODES + 63) / 64, 64, 0, stream>>>(cnt, perm);

    k_cvt_x<<<(N_NODES * IN_C / 4) / 256, 256, 0, stream>>>((const float4*)x, (short4*)Xb);
    k_prep_w<<<512, 256, 0, stream>>>(W1l, W1r, Wt);
    k_prep_w2f<<<20, 256, 0, stream>>>(W2l, W2r, Wt2f);

    k_gemm1<<<dim3((N_NODES + 63) / 64, 2), 256, 0, stream>>>(Xb, Wt, b1, AbS, Bh);
    k_aggs<<<8 * ((N_NODES + 63) / 64), 256, 0, stream>>>(AbS, cnt, slots, perm, Mean);
    k_l2<<<N_NODES / 4, 256, 0, stream>>>(Mean, Bh, Wt2f, b2, Cp, Dp);
    k_agg2<<<N_NODES / 8, 256, 0, stream>>>(Cp, Dp, cnt, slots, perm, out);
}

// Round 9
// 361.095 us; speedup vs baseline: 1.1216x; 1.0253x over previous
//
#include <hip/hip_runtime.h>
#include <hip/hip_bf16.h>

#define N_NODES 50000
#define N_EDGES 1600000
#define IN_C 256
#define HID_C 256
#define OUT_C 10
#define SLOT_CAP 96      // max degree bound; graph verified to pass with 96 since r4
#define NBUCKET 196      // ceil(50000/256) dst-buckets of 256 nodes
#define EBUF_CAP 9216    // per-bucket edge capacity; mean 8163, sigma 90 -> +11.7 sigma
#define EPB 8192         // edges per k_part block

typedef short bf16x8 __attribute__((ext_vector_type(8)));
typedef float f32x4 __attribute__((ext_vector_type(4)));
typedef unsigned short u16x4 __attribute__((ext_vector_type(4)));

static __device__ __forceinline__ float b2f(short v) {
    unsigned u = (unsigned)(unsigned short)v << 16;
    return __builtin_bit_cast(float, u);
}
static __device__ __forceinline__ short f2b(float f) {
    __hip_bfloat16 h = __float2bfloat16(f);
    return __builtin_bit_cast(short, h);
}

// ---------- phase A: partition edges into 196 dst-buckets (packed 4B records) ----------
// two-phase over 8192 edges/block: longer per-bucket runs -> ~10x less writeback
__global__ __launch_bounds__(256) void k_part(const int* __restrict__ src,
                                              const int* __restrict__ dst,
                                              int* __restrict__ g_cursor,
                                              int* __restrict__ ebuf) {
    __shared__ int hist[NBUCKET];
    __shared__ int base[NBUCKET];
    __shared__ int pos[NBUCKET];
    int tid = threadIdx.x;
    if (tid < NBUCKET) { hist[tid] = 0; pos[tid] = 0; }
    __syncthreads();
    int i0 = blockIdx.x * (EPB / 4);          // int4 index base
#pragma unroll
    for (int q = 0; q < EPB / 4 / 256; ++q) { // 8 iters
        int idx = i0 + q * 256 + tid;
        if (idx < N_EDGES / 4) {
            int4 d = ((const int4*)dst)[idx];
            atomicAdd(&hist[d.x >> 8], 1);
            atomicAdd(&hist[d.y >> 8], 1);
            atomicAdd(&hist[d.z >> 8], 1);
            atomicAdd(&hist[d.w >> 8], 1);
        }
    }
    __syncthreads();
    if (tid < NBUCKET && hist[tid] > 0)
        base[tid] = atomicAdd(&g_cursor[tid], hist[tid]);
    __syncthreads();
#pragma unroll
    for (int q = 0; q < EPB / 4 / 256; ++q) {
        int idx = i0 + q * 256 + tid;
        if (idx < N_EDGES / 4) {
            int4 s = ((const int4*)src)[idx];
            int4 d = ((const int4*)dst)[idx];
            int ss[4] = { s.x, s.y, s.z, s.w };
            int dd[4] = { d.x, d.y, d.z, d.w };
#pragma unroll
            for (int e = 0; e < 4; ++e) {
                int b = dd[e] >> 8;
                int p = base[b] + atomicAdd(&pos[b], 1);
                if (p < EBUF_CAP)
                    ebuf[b * EBUF_CAP + p] = ss[e] | ((dd[e] & 255) << 16);
            }
        }
    }
}

// ---------- phase B: one block per bucket -> COMPACT csr + per-node offsets ----------
// pass1 count, block-scan (4-entry aligned), pass2 scatter. csr ~3.3MB dense.
__global__ __launch_bounds__(256) void k_bucket(const int* __restrict__ ebuf,
                                                const int* __restrict__ g_cursor,
                                                int* __restrict__ gtot,
                                                int* __restrict__ cnt,
                                                int* __restrict__ noff,
                                                unsigned short* __restrict__ csr) {
    __shared__ int lcnt[256];
    __shared__ int loff[256];
    __shared__ int lds4[4];
    __shared__ int base_s;
    int b = blockIdx.x, tid = threadIdx.x;
    lcnt[tid] = 0;
    __syncthreads();
    int n_e = g_cursor[b];
    if (n_e > EBUF_CAP) n_e = EBUF_CAP;
    const int* eb = ebuf + b * EBUF_CAP;
    int n4 = n_e >> 2;
    for (int t = tid; t < n4; t += 256) {
        int4 v = ((const int4*)eb)[t];
        atomicAdd(&lcnt[(v.x >> 16) & 255], 1);
        atomicAdd(&lcnt[(v.y >> 16) & 255], 1);
        atomicAdd(&lcnt[(v.z >> 16) & 255], 1);
        atomicAdd(&lcnt[(v.w >> 16) & 255], 1);
    }
    for (int t = (n4 << 2) + tid; t < n_e; t += 256)
        atomicAdd(&lcnt[(eb[t] >> 16) & 255], 1);
    __syncthreads();
    int c = lcnt[tid];
    if (c > SLOT_CAP) c = SLOT_CAP;
    int alloc = (c + 3) & ~3;                 // 8B-aligned rows for u16x4 loads
    // inclusive block scan of alloc
    int lane = tid & 63, wv = tid >> 6;
    int x = alloc;
#pragma unroll
    for (int off = 1; off < 64; off <<= 1) {
        int t2 = __shfl_up(x, off, 64);
        if (lane >= off) x += t2;
    }
    if (lane == 63) lds4[wv] = x;
    __syncthreads();
    int add = 0;
#pragma unroll
    for (int w2 = 0; w2 < 3; ++w2) if (w2 < wv) add += lds4[w2];
    int incl = x + add;
    int excl = incl - alloc;
    loff[tid] = excl;
    if (tid == 255) base_s = atomicAdd(gtot, incl);
    __syncthreads();
    int base = base_s;
    int nid = b * 256 + tid;
    if (nid < N_NODES) { cnt[nid] = c; noff[nid] = base + excl; }
    lcnt[tid] = 0;
    __syncthreads();
    // pass 2: scatter into compact csr
    for (int t = tid; t < n4; t += 256) {
        int4 v = ((const int4*)eb)[t];
        int vv[4] = { v.x, v.y, v.z, v.w };
#pragma unroll
        for (int e = 0; e < 4; ++e) {
            int dl = (vv[e] >> 16) & 255;
            int p = atomicAdd(&lcnt[dl], 1);
            if (p < SLOT_CAP) csr[(size_t)base + loff[dl] + p] = (unsigned short)(vv[e] & 0xFFFF);
        }
    }
    for (int t = (n4 << 2) + tid; t < n_e; t += 256) {
        int vv = eb[t];
        int dl = (vv >> 16) & 255;
        int p = atomicAdd(&lcnt[dl], 1);
        if (p < SLOT_CAP) csr[(size_t)base + loff[dl] + p] = (unsigned short)(vv & 0xFFFF);
    }
}

// ---------- WINDOWED degree sort: rank-sort 64-node windows (preserves locality) ----------
__global__ __launch_bounds__(64) void k_sortw(const int* __restrict__ cnt,
                                              int* __restrict__ perm) {
    __shared__ int deg[64];
    int w = blockIdx.x, t = threadIdx.x;   // 782 windows
    int nid = w * 64 + t;
    bool valid = (nid < N_NODES);
    int n = valid ? cnt[nid] : 0x7FFFFFFF;
    deg[t] = n;
    __syncthreads();
    if (valid) {
        int rank = 0;
#pragma unroll 16
        for (int j = 0; j < 64; ++j) {
            int nj = deg[j];
            rank += (nj < n || (nj == n && j < t)) ? 1 : 0;
        }
        perm[w * 64 + rank] = nid;
    }
}

// ---------- prep ----------
__global__ void k_cvt_x(const float4* __restrict__ x, short4* __restrict__ xb) {
    int i = blockIdx.x * 256 + threadIdx.x;   // N_NODES*IN_C/4 threads exactly
    float4 v = x[i];
    short4 o = { f2b(v.x), f2b(v.y), f2b(v.z), f2b(v.w) };
    xb[i] = o;
}

// Wt[n][k], n in [0,512): n<256 -> W1l[k][n], else W1r[k][n-256]
__global__ void k_prep_w(const float* __restrict__ W1l, const float* __restrict__ W1r,
                         __hip_bfloat16* __restrict__ Wt) {
    int idx = blockIdx.x * 256 + threadIdx.x;  // 512*256
    int n = idx >> 8, k = idx & 255;
    float v = (n < HID_C) ? W1l[k * HID_C + n] : W1r[k * HID_C + (n - HID_C)];
    Wt[idx] = __float2bfloat16(v);
}

// Wt2f rows 0..9 = W2l^T, rows 16..25 = W2r^T, fp32, stride 256
__global__ void k_prep_w2f(const float* __restrict__ W2l, const float* __restrict__ W2r,
                           float* __restrict__ Wt2f) {
    int idx = blockIdx.x * 256 + threadIdx.x;  // 20*256
    int r = idx >> 8, k = idx & 255;
    if (r < OUT_C) Wt2f[r * 256 + k] = W2l[k * OUT_C + r];
    else           Wt2f[(16 + r - OUT_C) * 256 + k] = W2r[k * OUT_C + (r - OUT_C)];
}

// ---------- GEMM1: [AbS | Bh] = Xb @ [W1l | W1r] (+b1 on Bh), 64x64 per wave ----------
// left half written CHANNEL-SLICED: AbS[slice][node][32]
__global__ __launch_bounds__(256) void k_gemm1(
        const __hip_bfloat16* __restrict__ Xb, const __hip_bfloat16* __restrict__ Wt,
        const float* __restrict__ b1,
        __hip_bfloat16* __restrict__ AbS, __hip_bfloat16* __restrict__ Bh) {
    int wave = threadIdx.x >> 6, lane = threadIdx.x & 63;
    int r = lane & 15, quad = lane >> 4;
    int m_base = blockIdx.x * 64;
    int n_base = blockIdx.y * 256 + wave * 64;

    const bf16x8* ap[4];
    const bf16x8* bp[4];
#pragma unroll
    for (int i = 0; i < 4; ++i) {
        int row = m_base + 16 * i + r;
        if (row > N_NODES - 1) row = N_NODES - 1;
        ap[i] = (const bf16x8*)(Xb + (size_t)row * IN_C + quad * 8);
        bp[i] = (const bf16x8*)(Wt + (size_t)(n_base + 16 * i + r) * IN_C + quad * 8);
    }
    f32x4 acc[4][4];
#pragma unroll
    for (int i = 0; i < 4; ++i)
#pragma unroll
        for (int j = 0; j < 4; ++j) acc[i][j] = f32x4{0.f, 0.f, 0.f, 0.f};

#pragma unroll
    for (int kk = 0; kk < IN_C / 32; ++kk) {
        bf16x8 a[4], b[4];
#pragma unroll
        for (int i = 0; i < 4; ++i) a[i] = ap[i][kk * 4];
#pragma unroll
        for (int j = 0; j < 4; ++j) b[j] = bp[j][kk * 4];
#pragma unroll
        for (int i = 0; i < 4; ++i)
#pragma unroll
            for (int j = 0; j < 4; ++j)
                acc[i][j] = __builtin_amdgcn_mfma_f32_16x16x32_bf16(a[i], b[j], acc[i][j], 0, 0, 0);
    }

    bool left = (n_base < HID_C);  // block-uniform
#pragma unroll
    for (int j = 0; j < 4; ++j) {
        int col = n_base + 16 * j + r;
        float bias = left ? 0.f : b1[col - HID_C];
        int sl = (col & 255) >> 5, cc = col & 31;
#pragma unroll
        for (int i = 0; i < 4; ++i) {
#pragma unroll
            for (int ii = 0; ii < 4; ++ii) {
                int row = m_base + 16 * i + quad * 4 + ii;
                if (row < N_NODES) {
                    float v = acc[i][j][ii];
                    if (left) AbS[((size_t)sl * N_NODES + row) * 32 + cc] = __float2bfloat16(v);
                    else      Bh[(size_t)row * HID_C + (col - HID_C)] = __float2bfloat16(v + bias);
                }
            }
        }
    }
}

// ---------- sliced mean-aggregation: slice = blockIdx & 7 (XCD round-robin) ----------
// 4 lanes own one node's 32-ch slice (8 ch each, 16B loads); compact csr rows.
__global__ __launch_bounds__(256) void k_aggs(
        const __hip_bfloat16* __restrict__ AbS, const int* __restrict__ cnt,
        const int* __restrict__ noff, const unsigned short* __restrict__ csr,
        const int* __restrict__ perm, __hip_bfloat16* __restrict__ Mean) {
    int b = blockIdx.x;                 // 8 * 782 = 6256
    int s = b & 7, g = b >> 3;          // slice, node-window
    int wave = threadIdx.x >> 6, lane = threadIdx.x & 63;
    int grp = lane >> 2;                // 0..15: node within wave
    int cp  = lane & 3;                 // channel chunk (8 ch)
    int idx = g * 64 + wave * 16 + grp;
    if (idx >= N_NODES) return;
    int nid = perm[idx];
    int n = cnt[nid];
    const unsigned short* row = csr + noff[nid];   // 8B-aligned (noff % 4 == 0)
    const __hip_bfloat16* base = AbS + (size_t)s * N_NODES * 32 + cp * 8;

    float a0[8], a1[8];
#pragma unroll
    for (int j = 0; j < 8; ++j) { a0[j] = 0.f; a1[j] = 0.f; }

    int e = 0;
    for (; e + 4 <= n; e += 4) {
        u16x4 r4 = *(const u16x4*)(row + e);   // 8B index prefetch (4 edges)
        bf16x8 v0 = *(const bf16x8*)(base + (size_t)r4[0] * 32);
        bf16x8 v1 = *(const bf16x8*)(base + (size_t)r4[1] * 32);
        bf16x8 v2 = *(const bf16x8*)(base + (size_t)r4[2] * 32);
        bf16x8 v3 = *(const bf16x8*)(base + (size_t)r4[3] * 32);
#pragma unroll
        for (int j = 0; j < 8; ++j) {
            a0[j] += b2f(v0[j]); a1[j] += b2f(v1[j]);
            a0[j] += b2f(v2[j]); a1[j] += b2f(v3[j]);
        }
    }
    for (; e < n; ++e) {
        bf16x8 v0 = *(const bf16x8*)(base + (size_t)row[e] * 32);
#pragma unroll
        for (int j = 0; j < 8; ++j) a0[j] += b2f(v0[j]);
    }

    float inv = 1.f / fmaxf((float)n, 1.f);
    bf16x8 o;
#pragma unroll
    for (int j = 0; j < 8; ++j) o[j] = f2b((a0[j] + a1[j]) * inv);
    *(bf16x8*)(Mean + (size_t)nid * HID_C + s * 32 + cp * 8) = o;
}

// ---------- relu(Mean + Bh) then h@W2l -> Cp, h@W2r+b2 -> Dp (packed stride 12) ----------
__global__ __launch_bounds__(256) void k_l2(
        const __hip_bfloat16* __restrict__ Mean, const __hip_bfloat16* __restrict__ Bh,
        const float* __restrict__ Wt2f, const float* __restrict__ b2,
        float* __restrict__ Cp, float* __restrict__ Dp) {
    int wave = threadIdx.x >> 6, lane = threadIdx.x & 63;
    int nid = blockIdx.x * 4 + wave;          // grid 12500 -> exact
    int half = lane >> 5;
    int c8 = (lane & 31) * 8;
    bf16x8 m  = *(const bf16x8*)(Mean + (size_t)nid * HID_C + c8);
    bf16x8 bb = *(const bf16x8*)(Bh + (size_t)nid * HID_C + c8);
    float h[8];
#pragma unroll
    for (int j = 0; j < 8; ++j)
        h[j] = fmaxf(b2f(m[j]) + b2f(bb[j]), 0.f);

    const float* wbase = Wt2f + (half ? 16 * 256 : 0);
    float acc[10];
#pragma unroll
    for (int j = 0; j < 10; ++j) {
        f32x4 w0 = *(const f32x4*)(wbase + j * 256 + c8);
        f32x4 w1 = *(const f32x4*)(wbase + j * 256 + c8 + 4);
        float a = h[0] * w0[0] + h[1] * w0[1] + h[2] * w0[2] + h[3] * w0[3]
                + h[4] * w1[0] + h[5] * w1[1] + h[6] * w1[2] + h[7] * w1[3];
#pragma unroll
        for (int off = 16; off > 0; off >>= 1)
            a += __shfl_down(a, off, 32);
        acc[j] = a;
    }
    if ((lane & 31) == 0) {
        if (half == 0) {
            float* o = Cp + (size_t)nid * 12;
#pragma unroll
            for (int j = 0; j < 10; ++j) o[j] = acc[j];
            o[10] = 0.f; o[11] = 0.f;
        } else {
            float* o = Dp + (size_t)nid * 12;
#pragma unroll
            for (int j = 0; j < 10; ++j) o[j] = acc[j] + b2[j];
        }
    }
}

// ---------- layer2 aggregation + log_softmax: two nodes per wave (32 lanes each) ----------
__global__ __launch_bounds__(256) void k_agg2(
        const float* __restrict__ Cp, const float* __restrict__ Dp,
        const int* __restrict__ cnt, const int* __restrict__ noff,
        const unsigned short* __restrict__ csr, const int* __restrict__ perm,
        float* __restrict__ out) {
    int wave = threadIdx.x >> 6, lane = threadIdx.x & 63;
    int half = lane >> 5, sub = lane & 31;
    int idx = blockIdx.x * 8 + wave * 2 + half;   // grid 6250 -> exact
    int nid = perm[idx];
    const unsigned short* row = csr + noff[nid];
    int n = cnt[nid];
    float s[10];
#pragma unroll
    for (int j = 0; j < 10; ++j) s[j] = 0.f;
    for (int e = sub; e < n; e += 32) {
        const float* cr = Cp + (size_t)row[e] * 12;
        f32x4 v0 = *(const f32x4*)cr;
        f32x4 v1 = *(const f32x4*)(cr + 4);
        f32x4 v2 = *(const f32x4*)(cr + 8);   // cols 8..11 (10,11 zeroed)
#pragma unroll
        for (int j = 0; j < 4; ++j) { s[j] += v0[j]; s[4 + j] += v1[j]; }
        s[8] += v2[0]; s[9] += v2[1];
    }
#pragma unroll
    for (int j = 0; j < 10; ++j)
#pragma unroll
        for (int off = 16; off > 0; off >>= 1)
            s[j] += __shfl_down(s[j], off, 32);
    if (sub == 0) {
        float inv = 1.f / fmaxf((float)n, 1.f);
        float z[10], mx = -1e30f;
#pragma unroll
        for (int j = 0; j < 10; ++j) {
            z[j] = s[j] * inv + Dp[(size_t)nid * 12 + j];
            mx = fmaxf(mx, z[j]);
        }
        float se = 0.f;
#pragma unroll
        for (int j = 0; j < 10; ++j) se += expf(z[j] - mx);
        float lse = logf(se) + mx;
#pragma unroll
        for (int j = 0; j < 10; ++j) out[(size_t)nid * OUT_C + j] = z[j] - lse;
    }
}

extern "C" void kernel_launch(void* const* d_in, const int* in_sizes, int n_in,
                              void* d_out, int out_size, void* d_ws, size_t ws_size,
                              hipStream_t stream) {
    const float* x   = (const float*)d_in[0];
    const int*   ei  = (const int*)d_in[1];
    const float* W1l = (const float*)d_in[2];
    const float* W1r = (const float*)d_in[3];
    const float* b1  = (const float*)d_in[4];
    const float* W2l = (const float*)d_in[5];
    const float* W2r = (const float*)d_in[6];
    const float* b2  = (const float*)d_in[7];
    float* out = (float*)d_out;
    const int* src = ei;
    const int* dst = ei + N_EDGES;

    char* w = (char*)d_ws;
    size_t off = 0;
    auto alloc = [&](size_t bytes) -> void* {
        void* p = w + off;
        off = (off + bytes + 255) & ~(size_t)255;
        return p;
    };
    __hip_bfloat16* Xb   = (__hip_bfloat16*)alloc((size_t)N_NODES * IN_C * 2);
    __hip_bfloat16* Wt   = (__hip_bfloat16*)alloc((size_t)2 * HID_C * IN_C * 2);
    float*          Wt2f = (float*)alloc((size_t)32 * 256 * 4);
    __hip_bfloat16* AbS  = (__hip_bfloat16*)alloc((size_t)N_NODES * HID_C * 2);
    __hip_bfloat16* Bh   = (__hip_bfloat16*)alloc((size_t)N_NODES * HID_C * 2);
    float* Cp = (float*)alloc((size_t)N_NODES * 12 * 4);
    float* Dp = (float*)alloc((size_t)N_NODES * 12 * 4);
    int* cnt      = (int*)alloc((size_t)N_NODES * 4);
    int* noff     = (int*)alloc((size_t)N_NODES * 4);
    unsigned short* csr = (unsigned short*)alloc((size_t)(N_EDGES + 4 * N_NODES) * 2);
    int* perm     = (int*)alloc((size_t)N_NODES * 4);
    int* g_cursor = (int*)alloc((size_t)(NBUCKET + 1) * 4);  // +1: gtot
    int* ebuf     = (int*)alloc((size_t)NBUCKET * EBUF_CAP * 4);
    int* gtot = g_cursor + NBUCKET;
    // Mean aliases Xb: Xb is dead after k_gemm1, Mean written by k_aggs afterwards
    __hip_bfloat16* Mean = Xb;

    hipMemsetAsync(g_cursor, 0, (size_t)(NBUCKET + 1) * 4, stream);

    k_part<<<(N_EDGES + EPB - 1) / EPB, 256, 0, stream>>>(src, dst, g_cursor, ebuf);
    k_bucket<<<NBUCKET, 256, 0, stream>>>(ebuf, g_cursor, gtot, cnt, noff, csr);
    k_sortw<<<(N_NODES + 63) / 64, 64, 0, stream>>>(cnt, perm);

    k_cvt_x<<<(N_NODES * IN_C / 4) / 256, 256, 0, stream>>>((const float4*)x, (short4*)Xb);
    k_prep_w<<<512, 256, 0, stream>>>(W1l, W1r, Wt);
    k_prep_w2f<<<20, 256, 0, stream>>>(W2l, W2r, Wt2f);

    k_gemm1<<<dim3((N_NODES + 63) / 64, 2), 256, 0, stream>>>(Xb, Wt, b1, AbS, Bh);
    k_aggs<<<8 * ((N_NODES + 63) / 64), 256, 0, stream>>>(AbS, cnt, noff, csr, perm, Mean);
    k_l2<<<N_NODES / 4, 256, 0, stream>>>(Mean, Bh, Wt2f, b2, Cp, Dp);
    k_agg2<<<N_NODES / 8, 256, 0, stream>>>(Cp, Dp, cnt, noff, csr, perm, out);
}